// Round 9
// baseline (265.837 us; speedup 1.0000x reference)
//
#include <hip/hip_runtime.h>
#include <cstdint>
#include <cstddef>

#define NQ 4
#define DIM 64
#define FAN 68
#define T_TOTAL 128
#define BATCH 4096

// DPP controls (gfx9): quad_perm = pattern byte; row_ror:N = 0x120|N
#define DPP_XOR1 0xB1   // quad_perm [1,0,3,2] : q ^ 1
#define DPP_XOR2 0x4E   // quad_perm [2,3,0,1] : q ^ 2
#define DPP_XOR3 0x1B   // quad_perm [3,2,1,0] : q ^ 3
#define DPP_ROR8 0x128  // row_ror:8 == lane ^ 8 within a 16-lane row
#define SWZ_XOR4 0x101F // ds_swizzle BitMode: xor_mask=4, and_mask=0x1F

template <int CTRL>
__device__ __forceinline__ float dppq(float x) {
    return __int_as_float(
        __builtin_amdgcn_update_dpp(0, __float_as_int(x), CTRL, 0xF, 0xF, true));
}

__device__ __forceinline__ float swz_xor4(float x) {
    return __int_as_float(__builtin_amdgcn_ds_swizzle(__float_as_int(x), SWZ_XOR4));
}

__device__ __forceinline__ float fastrcp(float x) {
    return __builtin_amdgcn_rcpf(x);
}

// K1: pre[row,16] = x[row,0:64] @ W[:,0:64]^T + b + theta   (row = t*B + b within chunk)
// slot order within the 16: (f,i,u,o) gate-major, wire-minor.
__global__ __launch_bounds__(256) void qlstm_pre(
    const float* __restrict__ x,   // [nrows, 64]
    const float* __restrict__ Wf, const float* __restrict__ bf,
    const float* __restrict__ Wi, const float* __restrict__ bi,
    const float* __restrict__ Wu, const float* __restrict__ bu,
    const float* __restrict__ Wo, const float* __restrict__ bo,
    const float* __restrict__ thetas,   // [4,4]
    float* __restrict__ pre,            // [nrows, 16]
    int nrows)
{
    int row = blockIdx.x * 256 + threadIdx.x;
    if (row >= nrows) return;

    const float4* xv = reinterpret_cast<const float4*>(x + (size_t)row * DIM);
    float4 xr[16];
#pragma unroll
    for (int j = 0; j < 16; ++j) xr[j] = xv[j];

    const float* Ws[4] = {Wf, Wi, Wu, Wo};
    const float* bs[4] = {bf, bi, bu, bo};

    float acc[16];
#pragma unroll
    for (int G = 0; G < 4; ++G) {
#pragma unroll
        for (int q = 0; q < NQ; ++q) {
            float a = bs[G][q] + thetas[G * NQ + q];
            const float4* wr = reinterpret_cast<const float4*>(Ws[G] + q * FAN);
#pragma unroll
            for (int j = 0; j < 16; ++j) {
                float4 w = wr[j];
                a = fmaf(xr[j].x, w.x, a);
                a = fmaf(xr[j].y, w.y, a);
                a = fmaf(xr[j].z, w.z, a);
                a = fmaf(xr[j].w, w.w, a);
            }
            acc[G * 4 + q] = a;
        }
    }

    float4* pv = reinterpret_cast<float4*>(pre + (size_t)row * 16);
#pragma unroll
    for (int k = 0; k < 4; ++k)
        pv[k] = make_float4(acc[4 * k], acc[4 * k + 1], acc[4 * k + 2], acc[4 * k + 3]);
}

// K2: recurrence, 16 lanes per batch element. lane-in-16 = G*4 + q,
// G: 0=I, 1=U, 2=F, 3=O ; q = wire. 64-thread block = 4 batch elems.
// Grid 1024 blocks -> 4 waves/CU (one per SIMD).
__global__ __launch_bounds__(64) void qlstm_rec(
    const float* __restrict__ pre,   // [chunkT, B, 16] (f,i,u,o)*4+q
    const float* __restrict__ Wf, const float* __restrict__ Wi,
    const float* __restrict__ Wu, const float* __restrict__ Wo,
    float* __restrict__ out,
    float* __restrict__ state,       // [2, B, 4]  (h then c)
    int t0, int chunkT, int isFirst, int isLast)
{
    const int tid = threadIdx.x;
    const int grp = tid & 15;
    const int G   = grp >> 2;      // 0=I,1=U,2=F,3=O
    const int q   = grp & 3;       // wire
    const int b   = blockIdx.x * 4 + (tid >> 4);

    const float* W = (G == 0) ? Wi : (G == 1) ? Wu : (G == 2) ? Wf : Wo;
    const int mG   = (G == 0) ? 1  : (G == 1) ? 2  : (G == 2) ? 0  : 3;  // pre slot

    // wh row for this (G,q), then key by wire relation (self, ^1, ^2, ^3)
    float w0 = W[q * FAN + DIM + 0];
    float w1 = W[q * FAN + DIM + 1];
    float w2 = W[q * FAN + DIM + 2];
    float w3 = W[q * FAN + DIM + 3];
    const int qA = q ^ 1, qB = q ^ 2, qC = q ^ 3;
    float wS = (q  == 0) ? w0 : (q  == 1) ? w1 : (q  == 2) ? w2 : w3;
    float wA = (qA == 0) ? w0 : (qA == 1) ? w1 : (qA == 2) ? w2 : w3;
    float wB = (qB == 0) ? w0 : (qB == 1) ? w1 : (qB == 2) ? w2 : w3;
    float wC = (qC == 0) ? w0 : (qC == 1) ? w1 : (qC == 2) ? w2 : w3;

    const bool is_u = (G == 1);
    const float Aa = is_u ?  2.0f :  1.0f;   // act = Aa*sigmoid(-nB*z)+Cc
    const float nB = is_u ? -2.0f : -1.0f;
    const float Cc = is_u ? -1.0f :  0.0f;

    float hS, cS;
    if (isFirst) {
        hS = 0.0f; cS = 0.0f;
    } else {
        hS = state[(size_t)b * 4 + q];
        cS = state[(size_t)BATCH * 4 + (size_t)b * 4 + q];
    }

    // per-lane pre element: elem = mG*4 + q ; stride per t = BATCH*16 floats
    const float* pptr = pre + ((size_t)b * 16 + mG * 4 + q);
    const size_t strideT = (size_t)BATCH * 16;

    // depth-4 register ring prefetch (4 B/lane/step)
    float ring[4];
#pragma unroll
    for (int d = 0; d < 4; ++d) {
        int td = (d < chunkT) ? d : (chunkT - 1);
        ring[d] = pptr[(size_t)td * strideT];
    }

    for (int tt = 0; tt < chunkT; tt += 4) {
#pragma unroll
        for (int u = 0; u < 4; ++u) {
            int t = tt + u;
            if (t >= chunkT) break;              // wave-uniform
            float p = ring[u];
            int tf = (t + 4 < chunkT) ? (t + 4) : (chunkT - 1);
            ring[u] = pptr[(size_t)tf * strideT];

            // gather h across wires (quad-local)
            float hA = dppq<DPP_XOR1>(hS);
            float hB = dppq<DPP_XOR2>(hS);
            float hC = dppq<DPP_XOR3>(hS);

            float a = p;
            a = fmaf(wS, hS, a);
            a = fmaf(wA, hA, a);
            a = fmaf(wB, hB, a);
            a = fmaf(wC, hC, a);

            float cg = __cosf(a);

            // z products: subsets per q (see derivation)
            float cA = dppq<DPP_XOR1>(cg);
            float cB = dppq<DPP_XOR2>(cg);
            float cC = dppq<DPP_XOR3>(cg);
            float s0 = (q == 0) ? 1.0f : cg;
            float s1 = (q == 2) ? 1.0f : cA;
            float s2 = (q == 1) ? 1.0f : cB;
            float s3 = (q == 1) ? 1.0f : cC;
            float z  = (s0 * s1) * (s2 * s3);

            // activation: sigmoid (I,F,O) / tanh (U)
            float e   = __expf(nB * z);
            float act = fmaf(Aa, fastrcp(1.0f + e), Cc);

            // gate-pair exchange (lane ^ 4): I<->U, F<->O
            float partner = swz_xor4(act);

            // prod: I,U lanes -> I*U ; F,O lanes -> F*c
            float xm = (G == 3) ? partner : act;
            float ym = (G >= 2) ? cS : partner;
            float prod = xm * ym;

            // c_new = I*U + F*c  (xor8 sum; identical on all 4 G-lanes of q)
            float cn = prod + dppq<DPP_ROR8>(prod);
            cS = cn;

            float e2  = __expf(-2.0f * cn);
            float tnh = fmaf(2.0f, fastrcp(1.0f + e2), -1.0f);

            // route O to all lanes: hi half has it (G=3 self, G=2 partner)
            float tmpO = (G == 2) ? partner : act;
            float OvH  = dppq<DPP_ROR8>(tmpO);
            float Ov   = (G < 2) ? OvH : tmpO;

            hS = Ov * tnh;

            if (G == 0)
                out[((size_t)(t0 + t) * BATCH + b) * 4 + q] = hS;
        }
    }

    // persist state for next chunk (single writer per address)
    if (G == 0) state[(size_t)b * 4 + q] = hS;
    if (G == 1) state[(size_t)BATCH * 4 + (size_t)b * 4 + q] = cS;

    if (isLast) {
        size_t tail = (size_t)T_TOTAL * BATCH * 4;
        if (G == 0) out[tail + (size_t)b * 4 + q] = hS;
        if (G == 1) out[tail + (size_t)BATCH * 4 + (size_t)b * 4 + q] = cS;
    }
}

extern "C" void kernel_launch(void* const* d_in, const int* in_sizes, int n_in,
                              void* d_out, int out_size, void* d_ws, size_t ws_size,
                              hipStream_t stream)
{
    const float* x  = (const float*)d_in[0];
    const float* Wf = (const float*)d_in[1];
    const float* bf = (const float*)d_in[2];
    const float* Wi = (const float*)d_in[3];
    const float* bi = (const float*)d_in[4];
    const float* Wu = (const float*)d_in[5];
    const float* bu = (const float*)d_in[6];
    const float* Wo = (const float*)d_in[7];
    const float* bo = (const float*)d_in[8];
    const float* th = (const float*)d_in[9];
    float* out = (float*)d_out;

    const size_t stateBytes = 2 * (size_t)BATCH * 4 * sizeof(float);  // 128 KB
    const size_t perT       = (size_t)BATCH * 16 * sizeof(float);     // 256 KB per timestep
    size_t avail = (ws_size > stateBytes) ? (ws_size - stateBytes) : 0;
    int chunkT = (int)(avail / perT);
    if (chunkT > T_TOTAL) chunkT = T_TOTAL;
    if (chunkT < 1) chunkT = 1;   // requires ws_size >= ~384KB

    float* pre = (float*)d_ws;
    size_t stateOff = (ws_size - stateBytes) & ~(size_t)15;
    float* state = (float*)((char*)d_ws + stateOff);

    for (int t0 = 0; t0 < T_TOTAL; t0 += chunkT) {
        int ct = (T_TOTAL - t0 < chunkT) ? (T_TOTAL - t0) : chunkT;
        int nrows = ct * BATCH;
        qlstm_pre<<<(nrows + 255) / 256, 256, 0, stream>>>(
            x + (size_t)t0 * BATCH * DIM,
            Wf, bf, Wi, bi, Wu, bu, Wo, bo, th, pre, nrows);
        // 4 batch elems per 64-thread block (16 lanes each) -> BATCH/4 = 1024 blocks
        qlstm_rec<<<BATCH / 4, 64, 0, stream>>>(
            pre, Wf, Wi, Wu, Wo, out, state,
            t0, ct, (t0 == 0) ? 1 : 0, (t0 + ct >= T_TOTAL) ? 1 : 0);
    }
}

// Round 11
// 251.795 us; speedup vs baseline: 1.0558x; 1.0558x over previous
//
#include <hip/hip_runtime.h>
#include <cstdint>
#include <cstddef>

#define NQ 4
#define DIM 64
#define FAN 68
#define T_TOTAL 128
#define BATCH 4096

// DPP controls (gfx9): quad_perm = pattern byte; row_ror:N = 0x120|N
#define DPP_XOR1 0xB1   // quad_perm [1,0,3,2] : q ^ 1
#define DPP_XOR2 0x4E   // quad_perm [2,3,0,1] : q ^ 2
#define DPP_XOR3 0x1B   // quad_perm [3,2,1,0] : q ^ 3
#define DPP_ROR8 0x128  // row_ror:8 == lane ^ 8 within a 16-lane row
#define SWZ_XOR4 0x101F // ds_swizzle BitMode: xor_mask=4, and_mask=0x1F

template <int CTRL>
__device__ __forceinline__ float dppq(float x) {
    return __int_as_float(
        __builtin_amdgcn_update_dpp(0, __float_as_int(x), CTRL, 0xF, 0xF, true));
}

__device__ __forceinline__ float swz_xor4(float x) {
    return __int_as_float(__builtin_amdgcn_ds_swizzle(__float_as_int(x), SWZ_XOR4));
}

__device__ __forceinline__ float fastrcp(float x) {
    return __builtin_amdgcn_rcpf(x);
}

// K1: pre[row,16] = x[row,0:64] @ W[:,0:64]^T + b + theta   (row = t*B + b within chunk)
// slot order within the 16: (f,i,u,o) gate-major, wire-minor.
__global__ __launch_bounds__(256) void qlstm_pre(
    const float* __restrict__ x,   // [nrows, 64]
    const float* __restrict__ Wf, const float* __restrict__ bf,
    const float* __restrict__ Wi, const float* __restrict__ bi,
    const float* __restrict__ Wu, const float* __restrict__ bu,
    const float* __restrict__ Wo, const float* __restrict__ bo,
    const float* __restrict__ thetas,   // [4,4]
    float* __restrict__ pre,            // [nrows, 16]
    int nrows)
{
    int row = blockIdx.x * 256 + threadIdx.x;
    if (row >= nrows) return;

    const float4* xv = reinterpret_cast<const float4*>(x + (size_t)row * DIM);
    float4 xr[16];
#pragma unroll
    for (int j = 0; j < 16; ++j) xr[j] = xv[j];

    const float* Ws[4] = {Wf, Wi, Wu, Wo};
    const float* bs[4] = {bf, bi, bu, bo};

    float acc[16];
#pragma unroll
    for (int G = 0; G < 4; ++G) {
#pragma unroll
        for (int q = 0; q < NQ; ++q) {
            float a = bs[G][q] + thetas[G * NQ + q];
            const float4* wr = reinterpret_cast<const float4*>(Ws[G] + q * FAN);
#pragma unroll
            for (int j = 0; j < 16; ++j) {
                float4 w = wr[j];
                a = fmaf(xr[j].x, w.x, a);
                a = fmaf(xr[j].y, w.y, a);
                a = fmaf(xr[j].z, w.z, a);
                a = fmaf(xr[j].w, w.w, a);
            }
            acc[G * 4 + q] = a;
        }
    }

    float4* pv = reinterpret_cast<float4*>(pre + (size_t)row * 16);
#pragma unroll
    for (int k = 0; k < 4; ++k)
        pv[k] = make_float4(acc[4 * k], acc[4 * k + 1], acc[4 * k + 2], acc[4 * k + 3]);
}

// ---- shared per-lane recurrence step (16 lanes per batch elem, lane = G*4+q) ----
struct RecCtx {
    float wS, wA, wB, wC;
    float Aa, nB, Cc;
    int G, q;
};

__device__ __forceinline__ void rec_step(const RecCtx& cx, float pv, float& hS, float& cS) {
    // gather h across wires (quad-local)
    float hA = dppq<DPP_XOR1>(hS);
    float hB = dppq<DPP_XOR2>(hS);
    float hC = dppq<DPP_XOR3>(hS);

    float a = pv;
    a = fmaf(cx.wS, hS, a);
    a = fmaf(cx.wA, hA, a);
    a = fmaf(cx.wB, hB, a);
    a = fmaf(cx.wC, hC, a);

    float cg = __cosf(a);

    // z products: subsets per q
    float cA = dppq<DPP_XOR1>(cg);
    float cB = dppq<DPP_XOR2>(cg);
    float cC = dppq<DPP_XOR3>(cg);
    float s0 = (cx.q == 0) ? 1.0f : cg;
    float s1 = (cx.q == 2) ? 1.0f : cA;
    float s2 = (cx.q == 1) ? 1.0f : cB;
    float s3 = (cx.q == 1) ? 1.0f : cC;
    float z  = (s0 * s1) * (s2 * s3);

    // activation: sigmoid (I,F,O) / tanh (U)
    float e   = __expf(cx.nB * z);
    float act = fmaf(cx.Aa, fastrcp(1.0f + e), cx.Cc);

    // gate-pair exchange (lane ^ 4): I<->U, F<->O
    float partner = swz_xor4(act);

    // prod: I,U lanes -> I*U ; F,O lanes -> F*c
    float xm = (cx.G == 3) ? partner : act;
    float ym = (cx.G >= 2) ? cS : partner;
    float prod = xm * ym;

    // c_new = I*U + F*c  (xor8 sum; identical on all 4 G-lanes of q)
    float cn = prod + dppq<DPP_ROR8>(prod);
    cS = cn;

    float e2  = __expf(-2.0f * cn);
    float tnh = fmaf(2.0f, fastrcp(1.0f + e2), -1.0f);

    // route O to all lanes: hi half has it (G=3 self, G=2 partner)
    float tmpO = (cx.G == 2) ? partner : act;
    float OvH  = dppq<DPP_ROR8>(tmpO);
    float Ov   = (cx.G < 2) ? OvH : tmpO;

    hS = Ov * tnh;
}

__device__ __forceinline__ RecCtx make_ctx(int G, int q,
    const float* __restrict__ Wf, const float* __restrict__ Wi,
    const float* __restrict__ Wu, const float* __restrict__ Wo) {
    RecCtx cx;
    cx.G = G; cx.q = q;
    const float* W = (G == 0) ? Wi : (G == 1) ? Wu : (G == 2) ? Wf : Wo;
    float w0 = W[q * FAN + DIM + 0];
    float w1 = W[q * FAN + DIM + 1];
    float w2 = W[q * FAN + DIM + 2];
    float w3 = W[q * FAN + DIM + 3];
    const int qA = q ^ 1, qB = q ^ 2, qC = q ^ 3;
    cx.wS = (q  == 0) ? w0 : (q  == 1) ? w1 : (q  == 2) ? w2 : w3;
    cx.wA = (qA == 0) ? w0 : (qA == 1) ? w1 : (qA == 2) ? w2 : w3;
    cx.wB = (qB == 0) ? w0 : (qB == 1) ? w1 : (qB == 2) ? w2 : w3;
    cx.wC = (qC == 0) ? w0 : (qC == 1) ? w1 : (qC == 2) ? w2 : w3;
    const bool is_u = (G == 1);
    cx.Aa = is_u ?  2.0f :  1.0f;
    cx.nB = is_u ? -2.0f : -1.0f;
    cx.Cc = is_u ? -1.0f :  0.0f;
    return cx;
}

// K2 (full-T path): whole recurrence in one dispatch; pre column staged in
// registers 32 steps at a time -> no memory latency inside the step chain.
__global__ __launch_bounds__(64) void qlstm_rec128(
    const float* __restrict__ pre,   // [128, B, 16] (f,i,u,o)*4+q
    const float* __restrict__ Wf, const float* __restrict__ Wi,
    const float* __restrict__ Wu, const float* __restrict__ Wo,
    float* __restrict__ out)
{
    const int tid = threadIdx.x;
    const int grp = tid & 15;
    const int G   = grp >> 2;
    const int q   = grp & 3;
    const int b   = blockIdx.x * 4 + (tid >> 4);

    const RecCtx cx = make_ctx(G, q, Wf, Wi, Wu, Wo);
    const int mG = (G == 0) ? 1 : (G == 1) ? 2 : (G == 2) ? 0 : 3;

    float hS = 0.0f, cS = 0.0f;
    const float* pptr = pre + ((size_t)b * 16 + mG * 4 + q);
    const size_t strideT = (size_t)BATCH * 16;

    for (int tc = 0; tc < T_TOTAL / 32; ++tc) {
        float p[32];
#pragma unroll
        for (int j = 0; j < 32; ++j)
            p[j] = pptr[(size_t)(tc * 32 + j) * strideT];
#pragma unroll
        for (int j = 0; j < 32; ++j) {
            rec_step(cx, p[j], hS, cS);
            if (G == 0)
                out[((size_t)(tc * 32 + j) * BATCH + b) * 4 + q] = hS;
        }
    }

    size_t tail = (size_t)T_TOTAL * BATCH * 4;
    if (G == 0) out[tail + (size_t)b * 4 + q] = hS;
    if (G == 1) out[tail + (size_t)BATCH * 4 + (size_t)b * 4 + q] = cS;
}

// K2 (chunked fallback, R9-proven): used only if ws can't hold all 128 steps.
__global__ __launch_bounds__(64) void qlstm_rec(
    const float* __restrict__ pre,
    const float* __restrict__ Wf, const float* __restrict__ Wi,
    const float* __restrict__ Wu, const float* __restrict__ Wo,
    float* __restrict__ out,
    float* __restrict__ state,
    int t0, int chunkT, int isFirst, int isLast)
{
    const int tid = threadIdx.x;
    const int grp = tid & 15;
    const int G   = grp >> 2;
    const int q   = grp & 3;
    const int b   = blockIdx.x * 4 + (tid >> 4);

    const RecCtx cx = make_ctx(G, q, Wf, Wi, Wu, Wo);
    const int mG = (G == 0) ? 1 : (G == 1) ? 2 : (G == 2) ? 0 : 3;

    float hS, cS;
    if (isFirst) { hS = 0.0f; cS = 0.0f; }
    else {
        hS = state[(size_t)b * 4 + q];
        cS = state[(size_t)BATCH * 4 + (size_t)b * 4 + q];
    }

    const float* pptr = pre + ((size_t)b * 16 + mG * 4 + q);
    const size_t strideT = (size_t)BATCH * 16;

    float ring[4];
#pragma unroll
    for (int d = 0; d < 4; ++d) {
        int td = (d < chunkT) ? d : (chunkT - 1);
        ring[d] = pptr[(size_t)td * strideT];
    }

    for (int tt = 0; tt < chunkT; tt += 4) {
#pragma unroll
        for (int u = 0; u < 4; ++u) {
            int t = tt + u;
            if (t >= chunkT) break;
            float pv = ring[u];
            int tf = (t + 4 < chunkT) ? (t + 4) : (chunkT - 1);
            ring[u] = pptr[(size_t)tf * strideT];

            rec_step(cx, pv, hS, cS);

            if (G == 0)
                out[((size_t)(t0 + t) * BATCH + b) * 4 + q] = hS;
        }
    }

    if (G == 0) state[(size_t)b * 4 + q] = hS;
    if (G == 1) state[(size_t)BATCH * 4 + (size_t)b * 4 + q] = cS;

    if (isLast) {
        size_t tail = (size_t)T_TOTAL * BATCH * 4;
        if (G == 0) out[tail + (size_t)b * 4 + q] = hS;
        if (G == 1) out[tail + (size_t)BATCH * 4 + (size_t)b * 4 + q] = cS;
    }
}

extern "C" void kernel_launch(void* const* d_in, const int* in_sizes, int n_in,
                              void* d_out, int out_size, void* d_ws, size_t ws_size,
                              hipStream_t stream)
{
    const float* x  = (const float*)d_in[0];
    const float* Wf = (const float*)d_in[1];
    const float* bf = (const float*)d_in[2];
    const float* Wi = (const float*)d_in[3];
    const float* bi = (const float*)d_in[4];
    const float* Wu = (const float*)d_in[5];
    const float* bu = (const float*)d_in[6];
    const float* Wo = (const float*)d_in[7];
    const float* bo = (const float*)d_in[8];
    const float* th = (const float*)d_in[9];
    float* out = (float*)d_out;

    const size_t stateBytes = 2 * (size_t)BATCH * 4 * sizeof(float);  // 128 KB
    const size_t perT       = (size_t)BATCH * 16 * sizeof(float);     // 256 KB per timestep
    size_t avail = (ws_size > stateBytes) ? (ws_size - stateBytes) : 0;
    int chunkT = (int)(avail / perT);
    if (chunkT > T_TOTAL) chunkT = T_TOTAL;
    if (chunkT < 1) chunkT = 1;

    float* pre = (float*)d_ws;
    size_t stateOff = (ws_size - stateBytes) & ~(size_t)15;
    float* state = (float*)((char*)d_ws + stateOff);

    if (chunkT >= T_TOTAL) {
        // single pass: pre for all 128 steps, then the full-T register-staged rec
        int nrows = T_TOTAL * BATCH;
        qlstm_pre<<<(nrows + 255) / 256, 256, 0, stream>>>(
            x, Wf, bf, Wi, bi, Wu, bu, Wo, bo, th, pre, nrows);
        qlstm_rec128<<<BATCH / 4, 64, 0, stream>>>(pre, Wf, Wi, Wu, Wo, out);
    } else {
        for (int t0 = 0; t0 < T_TOTAL; t0 += chunkT) {
            int ct = (T_TOTAL - t0 < chunkT) ? (T_TOTAL - t0) : chunkT;
            int nrows = ct * BATCH;
            qlstm_pre<<<(nrows + 255) / 256, 256, 0, stream>>>(
                x + (size_t)t0 * BATCH * DIM,
                Wf, bf, Wi, bi, Wu, bu, Wo, bo, th, pre, nrows);
            qlstm_rec<<<BATCH / 4, 64, 0, stream>>>(
                pre, Wf, Wi, Wu, Wo, out, state,
                t0, ct, (t0 == 0) ? 1 : 0, (t0 + ct >= T_TOTAL) ? 1 : 0);
        }
    }
}